// Round 7
// baseline (866.843 us; speedup 1.0000x reference)
//
#include <hip/hip_runtime.h>
#include <cstdint>
#include <cstddef>

#define BN_EPS 1e-5f
#define BK 64          // buckets (dst>>11); 100000>>11 = 48 -> 49 used
#define BSH 11
#define CHUNK 4096     // edges per block in hist/scatter

// ---- manual bf16 helpers (hip_bf16.h intrinsics unavailable in this ROCm) ----
__device__ __forceinline__ unsigned int f32_to_bf16_rne(float f) {
    unsigned int u = __float_as_uint(f);
    u += 0x7FFFu + ((u >> 16) & 1u);
    return u >> 16;
}
__device__ __forceinline__ unsigned int pack_bf16x2(float a, float b) {
    return f32_to_bf16_rne(a) | (f32_to_bf16_rne(b) << 16);
}
__device__ __forceinline__ float bf16_lo(unsigned int p) { return __uint_as_float(p << 16); }
__device__ __forceinline__ float bf16_hi(unsigned int p) { return __uint_as_float(p & 0xFFFF0000u); }
__device__ __forceinline__ float bf16u(unsigned short u) { return __uint_as_float(((unsigned int)u) << 16); }

// ---------------- bucketed CSR build ----------------
// Phase 1: per-(bucket,block) histogram H[b*G+g]
__global__ void hist64_kernel(const int* __restrict__ dst, int* __restrict__ H, int e, int G) {
    __shared__ int h[BK];
    int t = threadIdx.x, g = blockIdx.x;
    if (t < BK) h[t] = 0;
    __syncthreads();
    int base = g * CHUNK;
#pragma unroll
    for (int i = 0; i < CHUNK / 256; i++) {
        int idx = base + i * 256 + t;
        if (idx < e) atomicAdd(&h[dst[idx] >> BSH], 1);
    }
    __syncthreads();
    if (t < BK) H[t * G + g] = h[t];
}

// Phase 3: scatter (src,dst) into bucket-contiguous binned array.
__global__ void bin_scatter_kernel(const int* __restrict__ src, const int* __restrict__ dst,
                                   const int* __restrict__ Hscan, uint2* __restrict__ binned,
                                   int e, int G) {
    __shared__ int cur[BK];
    int t = threadIdx.x, g = blockIdx.x;
    if (t < BK) cur[t] = Hscan[t * G + g];
    __syncthreads();
    int base = g * CHUNK;
#pragma unroll
    for (int i = 0; i < CHUNK / 256; i++) {
        int idx = base + i * 256 + t;
        if (idx < e) {
            int s = src[idx], d = dst[idx];
            int pos = atomicAdd(&cur[d >> BSH], 1);
            uint2 v; v.x = (unsigned)s; v.y = (unsigned)d;
            binned[pos] = v;
        }
    }
}

// Per-bucket degree count with XCD affinity (bucket = blockIdx % 64 -> XCD b%8).
__global__ void count_deg_binned_kernel(const uint2* __restrict__ binned,
                                        const int* __restrict__ Hscan,
                                        int* __restrict__ cnt, int e, int G, int P) {
    int b = blockIdx.x & (BK - 1);
    int p = blockIdx.x >> 6;
    int s = Hscan[b * G];
    int en = (b < BK - 1) ? Hscan[(b + 1) * G] : e;
    long long len = en - s;
    int c0 = s + (int)(len * p / P);
    int c1 = s + (int)(len * (p + 1) / P);
    for (int i = c0 + threadIdx.x; i < c1; i += 256)
        atomicAdd(&cnt[binned[i].y], 1);
}

// Per-bucket CSR fill (atomic cursor + scattered store stay XCD-local).
__global__ void fill_binned_kernel(const uint2* __restrict__ binned,
                                   const int* __restrict__ Hscan,
                                   int* __restrict__ cursor, int* __restrict__ esrc,
                                   int e, int G, int P) {
    int b = blockIdx.x & (BK - 1);
    int p = blockIdx.x >> 6;
    int s = Hscan[b * G];
    int en = (b < BK - 1) ? Hscan[(b + 1) * G] : e;
    long long len = en - s;
    int c0 = s + (int)(len * p / P);
    int c1 = s + (int)(len * (p + 1) / P);
    for (int i = c0 + threadIdx.x; i < c1; i += 256) {
        uint2 ed = binned[i];
        int pos = atomicAdd(&cursor[ed.y], 1);
        esrc[pos] = (int)ed.x;
    }
}

__global__ void dinv_kernel(const int* __restrict__ cnt, float* __restrict__ dinv, int n) {
    int i = blockIdx.x * 256 + threadIdx.x;
    if (i < n) dinv[i] = rsqrtf((float)(cnt[i] + 1));   // +1 self-loop; always > 0
}

// ---- 3-phase device-wide exclusive scan: 1024 elements/block, 256 thr ----

__global__ void blocksum_kernel(const int* __restrict__ cnt, int* __restrict__ bsum, int n) {
    int t = threadIdx.x;
    int base = blockIdx.x * 1024 + t * 4;
    int s = 0;
    if (base + 3 < n) {
        int4 v = *(const int4*)&cnt[base];
        s = v.x + v.y + v.z + v.w;
    } else {
        for (int j = 0; j < 4; j++) if (base + j < n) s += cnt[base + j];
    }
    __shared__ int ls[256];
    ls[t] = s;
    __syncthreads();
    for (int off = 128; off > 0; off >>= 1) {
        if (t < off) ls[t] += ls[t + off];
        __syncthreads();
    }
    if (t == 0) bsum[blockIdx.x] = ls[0];
}

// single block, nb <= 256: exclusive scan of bsum in place
__global__ void scan_bsum_kernel(int* __restrict__ bsum, int nb) {
    int t = threadIdx.x;
    __shared__ int ls[256];
    int v = (t < nb) ? bsum[t] : 0;
    ls[t] = v;
    __syncthreads();
    for (int off = 1; off < 256; off <<= 1) {
        int p = (t >= off) ? ls[t - off] : 0;
        __syncthreads();
        ls[t] += p;
        __syncthreads();
    }
    if (t < nb) bsum[t] = ls[t] - v;   // inclusive -> exclusive
}

// generic: write exclusive scan to single output array
__global__ void scan_write1_kernel(const int* __restrict__ in, const int* __restrict__ bsum,
                                   int* __restrict__ out, int n) {
    int t = threadIdx.x;
    int base = blockIdx.x * 1024 + t * 4;
    int v[4];
    int s = 0;
    if (base + 3 < n) {
        int4 q = *(const int4*)&in[base];
        v[0] = q.x; v[1] = q.y; v[2] = q.z; v[3] = q.w;
        s = q.x + q.y + q.z + q.w;
    } else {
        for (int j = 0; j < 4; j++) { v[j] = (base + j < n) ? in[base + j] : 0; s += v[j]; }
    }
    __shared__ int ls[256];
    ls[t] = s;
    __syncthreads();
    for (int off = 1; off < 256; off <<= 1) {
        int p = (t >= off) ? ls[t - off] : 0;
        __syncthreads();
        ls[t] += p;
        __syncthreads();
    }
    int run = bsum[blockIdx.x] + ls[t] - s;
    if (base + 3 < n) {
        int4 r; r.x = run; r.y = run + v[0]; r.z = run + v[0] + v[1]; r.w = run + v[0] + v[1] + v[2];
        *(int4*)&out[base] = r;
    } else {
        for (int j = 0; j < 4; j++) {
            if (base + j < n) out[base + j] = run;
            run += v[j];
        }
    }
}

// variant writing rowptr + cursor copies
__global__ void scan_write_kernel(const int* __restrict__ cnt, const int* __restrict__ bsum,
                                  int* __restrict__ rowptr, int* __restrict__ cursor, int n) {
    int t = threadIdx.x;
    int base = blockIdx.x * 1024 + t * 4;
    int v[4];
    int s = 0;
    if (base + 3 < n) {
        int4 q = *(const int4*)&cnt[base];
        v[0] = q.x; v[1] = q.y; v[2] = q.z; v[3] = q.w;
        s = q.x + q.y + q.z + q.w;
    } else {
        for (int j = 0; j < 4; j++) { v[j] = (base + j < n) ? cnt[base + j] : 0; s += v[j]; }
    }
    __shared__ int ls[256];
    ls[t] = s;
    __syncthreads();
    for (int off = 1; off < 256; off <<= 1) {
        int p = (t >= off) ? ls[t - off] : 0;
        __syncthreads();
        ls[t] += p;
        __syncthreads();
    }
    int run = bsum[blockIdx.x] + ls[t] - s;
    if (base + 3 < n) {
        int4 r; r.x = run; r.y = run + v[0]; r.z = run + v[0] + v[1]; r.w = run + v[0] + v[1] + v[2];
        *(int4*)&rowptr[base] = r;
        *(int4*)&cursor[base] = r;
    } else {
        for (int j = 0; j < 4; j++) {
            if (base + j < n) { rowptr[base + j] = run; cursor[base + j] = run; }
            run += v[j];
        }
    }
}

// ---------------- GEMM: Y[n,OUTC](bf16) = act(X[n,128]) @ W[128,OUTC] ----------------

template <int OUTC>
__global__ __launch_bounds__(256) void gemm_kernel(const float* __restrict__ X,
                                                   const float* __restrict__ W,
                                                   const float* __restrict__ scale,
                                                   const float* __restrict__ shift,
                                                   unsigned int* __restrict__ Y, int n) {
    constexpr int RPT = (OUTC == 128) ? 8 : 4;  // rows per thread
    constexpr int CG  = OUTC / 4;               // col groups (4 cols each)
    __shared__ float lXT[128 * 68];             // [k][row], 34.8 KB
    const int t = threadIdx.x;
    const int base = blockIdx.x * 64;
    const bool bn = (scale != nullptr);

#pragma unroll
    for (int i = 0; i < 8; i++) {
        int id = i * 256 + t;
        int k  = id & 127;
        int r4 = id >> 7;  // 0..15
        float sc = 1.0f, sh = 0.0f;
        if (bn) { sc = scale[k]; sh = shift[k]; }
        float v[4];
#pragma unroll
        for (int j = 0; j < 4; j++) {
            int r = base + r4 * 4 + j;
            float xv = 0.0f;
            if (r < n) xv = X[(size_t)r * 128 + k];
            if (bn) xv = fmaxf(fmaf(xv, sc, sh), 0.0f);
            v[j] = xv;
        }
        float4 vv; vv.x = v[0]; vv.y = v[1]; vv.z = v[2]; vv.w = v[3];
        *(float4*)&lXT[k * 68 + r4 * 4] = vv;
    }
    __syncthreads();

    const int cg = t % CG;
    const int rg = t / CG;
    float acc[RPT][4];
#pragma unroll
    for (int i = 0; i < RPT; i++)
#pragma unroll
        for (int j = 0; j < 4; j++) acc[i][j] = 0.0f;

#pragma unroll 4
    for (int k = 0; k < 128; k++) {
        float4 b = *(const float4*)&W[k * OUTC + cg * 4];
        float a[RPT];
        *(float4*)&a[0] = *(const float4*)&lXT[k * 68 + rg * RPT];
        if constexpr (RPT == 8)
            *(float4*)&a[4] = *(const float4*)&lXT[k * 68 + rg * RPT + 4];
#pragma unroll
        for (int i = 0; i < RPT; i++) {
            acc[i][0] = fmaf(a[i], b.x, acc[i][0]);
            acc[i][1] = fmaf(a[i], b.y, acc[i][1]);
            acc[i][2] = fmaf(a[i], b.z, acc[i][2]);
            acc[i][3] = fmaf(a[i], b.w, acc[i][3]);
        }
    }

#pragma unroll
    for (int i = 0; i < RPT; i++) {
        int r = base + rg * RPT + i;
        if (r < n) {
            uint2 o;
            o.x = pack_bf16x2(acc[i][0], acc[i][1]);
            o.y = pack_bf16x2(acc[i][2], acc[i][3]);
            *(uint2*)&Y[(size_t)r * (OUTC / 2) + cg * 2] = o;
        }
    }
}

// ---------------- aggregation (128-col layers): column-split halves ----------------
// Each pass handles 64 columns [coloff, coloff+64): lane = one bf16 column.
// Working set per pass = 12.8MB (vs 25.6) -> higher L2 hit rate on the gather.
// Persistent blocks (node-stride) carry BN partial sums in registers; one
// atomicAdd per column per block at the end replaces the bn_stats kernel.

__global__ __launch_bounds__(256) void agg128_half_kernel(const unsigned short* __restrict__ xw,
                                                          const int* __restrict__ rowptr,
                                                          const int* __restrict__ cnt,
                                                          const int* __restrict__ esrc,
                                                          const float* __restrict__ dinv,
                                                          const float* __restrict__ bias,
                                                          float* __restrict__ out,
                                                          float* __restrict__ sums,
                                                          int n, int coloff) {
    const int wave   = (blockIdx.x * 256 + threadIdx.x) >> 6;
    const int lane   = threadIdx.x & 63;
    const int nwaves = gridDim.x * 4;
    const int col    = coloff + lane;
    const float bcol = bias[col];
    float psum = 0.0f, psq = 0.0f;

    for (int node = wave; node < n; node += nwaves) {
        float di = dinv[node];
        float sw = di * di;
        int beg = rowptr[node];
        int end = beg + cnt[node];
        float acc = sw * bf16u(xw[(size_t)node * 128 + col]);
        int e = beg;
        for (; e + 8 <= end; e += 8) {
            int s[8];
#pragma unroll
            for (int j = 0; j < 8; j++) s[j] = esrc[e + j];
            float w[8];
            unsigned short v[8];
#pragma unroll
            for (int j = 0; j < 8; j++) {
                w[j] = dinv[s[j]];
                v[j] = xw[(size_t)s[j] * 128 + col];
            }
#pragma unroll
            for (int j = 0; j < 8; j++) acc = fmaf(w[j] * di, bf16u(v[j]), acc);
        }
        for (; e < end; e++) {
            int s = esrc[e];
            acc = fmaf(dinv[s] * di, bf16u(xw[(size_t)s * 128 + col]), acc);
        }
        float o = acc + bcol;
        out[(size_t)node * 128 + col] = o;
        psum += o;
        psq = fmaf(o, o, psq);
    }

    __shared__ float ls[256], lq[256];
    ls[threadIdx.x] = psum;
    lq[threadIdx.x] = psq;
    __syncthreads();
    if (threadIdx.x < 64) {
        float s = ls[threadIdx.x] + ls[threadIdx.x + 64] + ls[threadIdx.x + 128] + ls[threadIdx.x + 192];
        float q = lq[threadIdx.x] + lq[threadIdx.x + 64] + lq[threadIdx.x + 128] + lq[threadIdx.x + 192];
        atomicAdd(&sums[col], s);
        atomicAdd(&sums[128 + col], q);
    }
}

// ---------------- aggregation (64-col output layer, bf16 packed) ----------------

__global__ __launch_bounds__(256) void agg64_kernel(const unsigned int* __restrict__ xw,
                                                    const int* __restrict__ rowptr,
                                                    const int* __restrict__ cnt,
                                                    const int* __restrict__ esrc,
                                                    const float* __restrict__ dinv,
                                                    const float* __restrict__ bias,
                                                    float* __restrict__ out, int n) {
    int gid = blockIdx.x * 256 + threadIdx.x;
    int node = gid >> 6;
    int lane = gid & 63;
    if (node >= n) return;
    float di = dinv[node];
    float sw = di * di;
    int beg = rowptr[node];
    int end = beg + cnt[node];

    unsigned int ap = xw[(size_t)node * 32 + (lane >> 1)];
    float a0 = (lane & 1) ? bf16_hi(ap) : bf16_lo(ap);
    float acc = sw * a0;
    int e = beg;
    for (; e + 8 <= end; e += 8) {
        int s[8];
#pragma unroll
        for (int j = 0; j < 8; j++) s[j] = esrc[e + j];
        float w[8];
        unsigned int v[8];
#pragma unroll
        for (int j = 0; j < 8; j++) {
            w[j] = dinv[s[j]];
            v[j] = xw[(size_t)s[j] * 32 + (lane >> 1)];
        }
#pragma unroll
        for (int j = 0; j < 8; j++) {
            float vf = (lane & 1) ? bf16_hi(v[j]) : bf16_lo(v[j]);
            acc = fmaf(w[j] * di, vf, acc);
        }
    }
    for (; e < end; e++) {
        int s = esrc[e];
        unsigned int v = xw[(size_t)s * 32 + (lane >> 1)];
        float vf = (lane & 1) ? bf16_hi(v) : bf16_lo(v);
        acc = fmaf(dinv[s] * di, vf, acc);
    }
    out[(size_t)node * 64 + lane] = acc + bias[lane];
}

// ---------------- BatchNorm finalize ----------------

__global__ void bn_finalize_kernel(const float* __restrict__ sums, const float* __restrict__ g,
                                   const float* __restrict__ be, float* __restrict__ scale,
                                   float* __restrict__ shift, int n) {
    int c = threadIdx.x;  // 128 threads
    float inv_n = 1.0f / (float)n;
    float mean = sums[c] * inv_n;
    float var = sums[128 + c] * inv_n - mean * mean;
    float rstd = rsqrtf(var + BN_EPS);
    float sc = rstd * g[c];
    scale[c] = sc;
    shift[c] = be[c] - mean * sc;
}

// ---------------- launch ----------------

extern "C" void kernel_launch(void* const* d_in, const int* in_sizes, int n_in,
                              void* d_out, int out_size, void* d_ws, size_t ws_size,
                              hipStream_t stream) {
    const float* x   = (const float*)d_in[0];
    const int*   ei  = (const int*)d_in[1];
    const float* W1  = (const float*)d_in[2];
    const float* b1  = (const float*)d_in[3];
    const float* g1  = (const float*)d_in[4];
    const float* be1 = (const float*)d_in[5];
    const float* W2  = (const float*)d_in[6];
    const float* b2  = (const float*)d_in[7];
    const float* g2  = (const float*)d_in[8];
    const float* be2 = (const float*)d_in[9];
    const float* W3  = (const float*)d_in[10];
    const float* b3  = (const float*)d_in[11];

    const int n = in_sizes[0] / 128;
    const int E = in_sizes[1] / 2;
    const int* srcv = ei;
    const int* dstv = ei + E;

    const int G = (E + CHUNK - 1) / CHUNK;      // hist/scatter blocks (391)
    const int HN = BK * G;                       // H matrix elements (25024)

    char* p = (char*)d_ws;
    auto carve = [&](size_t bytes) -> char* {
        char* q = p;
        p += (bytes + 255) & ~(size_t)255;
        return q;
    };
    int*   cnt    = (int*)carve((size_t)n * 4);
    int*   rowptr = (int*)carve((size_t)n * 4);
    int*   cursor = (int*)carve((size_t)n * 4);
    float* dinv   = (float*)carve((size_t)n * 4);
    int*   esrc   = (int*)carve((size_t)E * 4);
    uint2* binned = (uint2*)carve((size_t)E * 8);
    int*   H      = (int*)carve((size_t)HN * 4);
    int*   Hscan  = (int*)carve((size_t)HN * 4);
    float* sums   = (float*)carve(512 * 4);   // [sum1|sq1|sum2|sq2]
    float* bnsc   = (float*)carve(512 * 4);   // [scale1|shift1|scale2|shift2]
    int*   bsum   = (int*)carve(1024 * 4);
    unsigned int* xwb = (unsigned int*)carve((size_t)n * 128 * 2);  // gemm out (bf16 packed)
    float* bufB   = (float*)carve((size_t)n * 128 * 4);             // agg out (fp32)

    hipMemsetAsync(cnt, 0, (size_t)n * 4, stream);
    hipMemsetAsync(sums, 0, 512 * 4, stream);

    int nb  = (n + 255) / 256;
    int sbH = (HN + 1023) / 1024;    // 25
    int sbN = (n + 1023) / 1024;     // 98
    const int P = 16;                // blocks per bucket in binned kernels

    // bucketed CSR build
    hist64_kernel<<<G, 256, 0, stream>>>(dstv, H, E, G);
    blocksum_kernel<<<sbH, 256, 0, stream>>>(H, bsum, HN);
    scan_bsum_kernel<<<1, 256, 0, stream>>>(bsum, sbH);
    scan_write1_kernel<<<sbH, 256, 0, stream>>>(H, bsum, Hscan, HN);
    bin_scatter_kernel<<<G, 256, 0, stream>>>(srcv, dstv, Hscan, binned, E, G);
    count_deg_binned_kernel<<<BK * P, 256, 0, stream>>>(binned, Hscan, cnt, E, G, P);
    dinv_kernel<<<nb, 256, 0, stream>>>(cnt, dinv, n);
    blocksum_kernel<<<sbN, 256, 0, stream>>>(cnt, bsum, n);
    scan_bsum_kernel<<<1, 256, 0, stream>>>(bsum, sbN);
    scan_write_kernel<<<sbN, 256, 0, stream>>>(cnt, bsum, rowptr, cursor, n);
    fill_binned_kernel<<<BK * P, 256, 0, stream>>>(binned, Hscan, cursor, esrc, E, G, P);

    int gb = (n + 63) / 64;
    int ab = (n + 3) / 4;
    const int AG = 2048;                             // persistent agg blocks (8/CU)
    const unsigned short* xwu16 = (const unsigned short*)xwb;

    // layer 1: gcn(x, W1) + b1   (BN stats fused into agg halves)
    gemm_kernel<128><<<gb, 256, 0, stream>>>(x, W1, nullptr, nullptr, xwb, n);
    agg128_half_kernel<<<AG, 256, 0, stream>>>(xwu16, rowptr, cnt, esrc, dinv, b1, bufB, sums, n, 0);
    agg128_half_kernel<<<AG, 256, 0, stream>>>(xwu16, rowptr, cnt, esrc, dinv, b1, bufB, sums, n, 64);
    bn_finalize_kernel<<<1, 128, 0, stream>>>(sums, g1, be1, bnsc, bnsc + 128, n);

    // layer 2: gcn(relu(bn1(h)), W2) + b2   (bn1+relu fused into gemm staging)
    gemm_kernel<128><<<gb, 256, 0, stream>>>(bufB, W2, bnsc, bnsc + 128, xwb, n);
    agg128_half_kernel<<<AG, 256, 0, stream>>>(xwu16, rowptr, cnt, esrc, dinv, b2, bufB, sums + 256, n, 0);
    agg128_half_kernel<<<AG, 256, 0, stream>>>(xwu16, rowptr, cnt, esrc, dinv, b2, bufB, sums + 256, n, 64);
    bn_finalize_kernel<<<1, 128, 0, stream>>>(sums + 256, g2, be2, bnsc + 256, bnsc + 384, n);

    // layer 3: gcn(relu(bn2(h)), W3) + b3  -> d_out
    gemm_kernel<64><<<gb, 256, 0, stream>>>(bufB, W3, bnsc + 256, bnsc + 384, xwb, n);
    agg64_kernel<<<ab, 256, 0, stream>>>(xwb, rowptr, cnt, esrc, dinv, b3, (float*)d_out, n);
}

// Round 8
// 695.193 us; speedup vs baseline: 1.2469x; 1.2469x over previous
//
#include <hip/hip_runtime.h>
#include <cstdint>
#include <cstddef>

#define BN_EPS 1e-5f
#define BKT 256        // buckets (dst>>9), 512 nodes each; 100000>>9 = 195 -> 196 used
#define BSH 9
#define CHUNK 8192     // edges per block in hist/scatter

// ---- manual bf16 helpers (hip_bf16.h intrinsics unavailable in this ROCm) ----
__device__ __forceinline__ unsigned int f32_to_bf16_rne(float f) {
    unsigned int u = __float_as_uint(f);
    u += 0x7FFFu + ((u >> 16) & 1u);
    return u >> 16;
}
__device__ __forceinline__ unsigned int pack_bf16x2(float a, float b) {
    return f32_to_bf16_rne(a) | (f32_to_bf16_rne(b) << 16);
}
__device__ __forceinline__ float bf16_lo(unsigned int p) { return __uint_as_float(p << 16); }
__device__ __forceinline__ float bf16_hi(unsigned int p) { return __uint_as_float(p & 0xFFFF0000u); }

// ---------------- bucketed CSR build ----------------
// Phase 1: per-(bucket,block) histogram H[b*G+g]
__global__ void hist_kernel(const int* __restrict__ dst, int* __restrict__ H, int e, int G) {
    __shared__ int h[BKT];
    int t = threadIdx.x, g = blockIdx.x;
    h[t] = 0;
    __syncthreads();
    int base = g * CHUNK;
#pragma unroll
    for (int i = 0; i < CHUNK / 256; i++) {
        int idx = base + i * 256 + t;
        if (idx < e) atomicAdd(&h[dst[idx] >> BSH], 1);
    }
    __syncthreads();
    H[t * G + g] = h[t];
}

// Phase 3: scatter (src,dst) into bucket-contiguous binned array.
__global__ void bin_scatter_kernel(const int* __restrict__ src, const int* __restrict__ dst,
                                   const int* __restrict__ Hscan, uint2* __restrict__ binned,
                                   int e, int G) {
    __shared__ int cur[BKT];
    int t = threadIdx.x, g = blockIdx.x;
    cur[t] = Hscan[t * G + g];
    __syncthreads();
    int base = g * CHUNK;
#pragma unroll
    for (int i = 0; i < CHUNK / 256; i++) {
        int idx = base + i * 256 + t;
        if (idx < e) {
            int s = src[idx], d = dst[idx];
            int pos = atomicAdd(&cur[d >> BSH], 1);
            uint2 v; v.x = (unsigned)s; v.y = (unsigned)d;
            binned[pos] = v;
        }
    }
}

// Phase 4: one block per bucket (512 nodes). Count degrees, local scan,
// write cnt/rowptr/dinv, then fill esrc -- all cursors/counts in LDS.
__global__ __launch_bounds__(256) void bucket_build_kernel(const uint2* __restrict__ binned,
                                                           const int* __restrict__ Hscan,
                                                           int* __restrict__ cnt,
                                                           int* __restrict__ rowptr,
                                                           float* __restrict__ dinv,
                                                           int* __restrict__ esrc,
                                                           int e, int G, int n) {
    __shared__ int lcnt[512], lexc[512], ssum[256];
    const int t = threadIdx.x;
    const int b = blockIdx.x;
    const int start = Hscan[b * G];
    const int end = (b == BKT - 1) ? e : Hscan[(b + 1) * G];

    lcnt[t] = 0; lcnt[t + 256] = 0;
    __syncthreads();
    for (int i = start + t; i < end; i += 256)
        atomicAdd(&lcnt[binned[i].y & 511], 1);
    __syncthreads();

    int a0 = lcnt[2 * t], a1 = lcnt[2 * t + 1];
    ssum[t] = a0 + a1;
    __syncthreads();
    for (int off = 1; off < 256; off <<= 1) {
        int v = (t >= off) ? ssum[t - off] : 0;
        __syncthreads();
        ssum[t] += v;
        __syncthreads();
    }
    int excl = (t == 0) ? 0 : ssum[t - 1];
    lexc[2 * t] = excl;
    lexc[2 * t + 1] = excl + a0;
    __syncthreads();

    int nodebase = b << BSH;
#pragma unroll
    for (int j2 = 0; j2 < 2; j2++) {
        int j = 2 * t + j2;
        int node = nodebase + j;
        if (node < n) {
            int c = lcnt[j];
            cnt[node] = c;
            rowptr[node] = start + lexc[j];
            dinv[node] = rsqrtf((float)(c + 1));
        }
    }
    __syncthreads();

    for (int i = start + t; i < end; i += 256) {
        uint2 ed = binned[i];
        int pos = start + atomicAdd(&lexc[ed.y & 511], 1);
        esrc[pos] = (int)ed.x;
    }
}

// ---- scan helpers for H (bucket-major (bucket,block) histogram) ----

__global__ void blocksum_kernel(const int* __restrict__ in, int* __restrict__ bsum, int n) {
    int t = threadIdx.x;
    int base = blockIdx.x * 1024 + t * 4;
    int s = 0;
    if (base + 3 < n) {
        int4 v = *(const int4*)&in[base];
        s = v.x + v.y + v.z + v.w;
    } else {
        for (int j = 0; j < 4; j++) if (base + j < n) s += in[base + j];
    }
    __shared__ int ls[256];
    ls[t] = s;
    __syncthreads();
    for (int off = 128; off > 0; off >>= 1) {
        if (t < off) ls[t] += ls[t + off];
        __syncthreads();
    }
    if (t == 0) bsum[blockIdx.x] = ls[0];
}

__global__ void scan_bsum_kernel(int* __restrict__ bsum, int nb) {
    int t = threadIdx.x;
    __shared__ int ls[256];
    int v = (t < nb) ? bsum[t] : 0;
    ls[t] = v;
    __syncthreads();
    for (int off = 1; off < 256; off <<= 1) {
        int p = (t >= off) ? ls[t - off] : 0;
        __syncthreads();
        ls[t] += p;
        __syncthreads();
    }
    if (t < nb) bsum[t] = ls[t] - v;   // inclusive -> exclusive
}

__global__ void scan_write1_kernel(const int* __restrict__ in, const int* __restrict__ bsum,
                                   int* __restrict__ out, int n) {
    int t = threadIdx.x;
    int base = blockIdx.x * 1024 + t * 4;
    int v[4];
    int s = 0;
    if (base + 3 < n) {
        int4 q = *(const int4*)&in[base];
        v[0] = q.x; v[1] = q.y; v[2] = q.z; v[3] = q.w;
        s = q.x + q.y + q.z + q.w;
    } else {
        for (int j = 0; j < 4; j++) { v[j] = (base + j < n) ? in[base + j] : 0; s += v[j]; }
    }
    __shared__ int ls[256];
    ls[t] = s;
    __syncthreads();
    for (int off = 1; off < 256; off <<= 1) {
        int p = (t >= off) ? ls[t - off] : 0;
        __syncthreads();
        ls[t] += p;
        __syncthreads();
    }
    int run = bsum[blockIdx.x] + ls[t] - s;
    if (base + 3 < n) {
        int4 r; r.x = run; r.y = run + v[0]; r.z = run + v[0] + v[1]; r.w = run + v[0] + v[1] + v[2];
        *(int4*)&out[base] = r;
    } else {
        for (int j = 0; j < 4; j++) {
            if (base + j < n) out[base + j] = run;
            run += v[j];
        }
    }
}

// ---------------- GEMM: Y[n,OUTC](bf16) = act(X[n,128]) @ W[128,OUTC] ----------------

template <int OUTC>
__global__ __launch_bounds__(256) void gemm_kernel(const float* __restrict__ X,
                                                   const float* __restrict__ W,
                                                   const float* __restrict__ scale,
                                                   const float* __restrict__ shift,
                                                   unsigned int* __restrict__ Y, int n) {
    constexpr int RPT = (OUTC == 128) ? 8 : 4;  // rows per thread
    constexpr int CG  = OUTC / 4;               // col groups (4 cols each)
    __shared__ float lXT[128 * 68];             // [k][row], 34.8 KB
    const int t = threadIdx.x;
    const int base = blockIdx.x * 64;
    const bool bn = (scale != nullptr);

#pragma unroll
    for (int i = 0; i < 8; i++) {
        int id = i * 256 + t;
        int k  = id & 127;
        int r4 = id >> 7;  // 0..15
        float sc = 1.0f, sh = 0.0f;
        if (bn) { sc = scale[k]; sh = shift[k]; }
        float v[4];
#pragma unroll
        for (int j = 0; j < 4; j++) {
            int r = base + r4 * 4 + j;
            float xv = 0.0f;
            if (r < n) xv = X[(size_t)r * 128 + k];
            if (bn) xv = fmaxf(fmaf(xv, sc, sh), 0.0f);
            v[j] = xv;
        }
        float4 vv; vv.x = v[0]; vv.y = v[1]; vv.z = v[2]; vv.w = v[3];
        *(float4*)&lXT[k * 68 + r4 * 4] = vv;
    }
    __syncthreads();

    const int cg = t % CG;
    const int rg = t / CG;
    float acc[RPT][4];
#pragma unroll
    for (int i = 0; i < RPT; i++)
#pragma unroll
        for (int j = 0; j < 4; j++) acc[i][j] = 0.0f;

#pragma unroll 4
    for (int k = 0; k < 128; k++) {
        float4 b = *(const float4*)&W[k * OUTC + cg * 4];
        float a[RPT];
        *(float4*)&a[0] = *(const float4*)&lXT[k * 68 + rg * RPT];
        if constexpr (RPT == 8)
            *(float4*)&a[4] = *(const float4*)&lXT[k * 68 + rg * RPT + 4];
#pragma unroll
        for (int i = 0; i < RPT; i++) {
            acc[i][0] = fmaf(a[i], b.x, acc[i][0]);
            acc[i][1] = fmaf(a[i], b.y, acc[i][1]);
            acc[i][2] = fmaf(a[i], b.z, acc[i][2]);
            acc[i][3] = fmaf(a[i], b.w, acc[i][3]);
        }
    }

#pragma unroll
    for (int i = 0; i < RPT; i++) {
        int r = base + rg * RPT + i;
        if (r < n) {
            uint2 o;
            o.x = pack_bf16x2(acc[i][0], acc[i][1]);
            o.y = pack_bf16x2(acc[i][2], acc[i][3]);
            *(uint2*)&Y[(size_t)r * (OUTC / 2) + cg * 2] = o;
        }
    }
}

// ---------------- aggregation (128 cols, persistent, fused BN partials) ----------------
// out[i] = sum_{e:dst=i} dinv[src_e]*dinv[i] * xw[src_e] + dinv[i]^2 * xw[i] + bias
// One wave per node (node-strided); lane owns cols 2l,2l+1 via one uint gather (4B).
// BN partial sums carried in registers, committed once per block.

__global__ __launch_bounds__(256) void agg128_kernel(const unsigned int* __restrict__ xw,
                                                     const int* __restrict__ rowptr,
                                                     const int* __restrict__ cnt,
                                                     const int* __restrict__ esrc,
                                                     const float* __restrict__ dinv,
                                                     const float* __restrict__ bias,
                                                     float* __restrict__ out,
                                                     float* __restrict__ sums, int n) {
    const int wave   = (blockIdx.x * 256 + threadIdx.x) >> 6;
    const int lane   = threadIdx.x & 63;
    const int nwaves = gridDim.x * 4;
    const float2 bc  = ((const float2*)bias)[lane];
    float psx = 0.0f, psy = 0.0f, pqx = 0.0f, pqy = 0.0f;

    for (int node = wave; node < n; node += nwaves) {
        float di = dinv[node];
        float sw = di * di;
        int beg = rowptr[node];
        int end = beg + cnt[node];
        unsigned int ap = xw[(size_t)node * 64 + lane];
        float ax = sw * bf16_lo(ap), ay = sw * bf16_hi(ap);
        int e = beg;
        for (; e + 8 <= end; e += 8) {
            int s[8];
#pragma unroll
            for (int j = 0; j < 8; j++) s[j] = esrc[e + j];
            float w[8];
            unsigned int v[8];
#pragma unroll
            for (int j = 0; j < 8; j++) {
                w[j] = dinv[s[j]];
                v[j] = xw[(size_t)s[j] * 64 + lane];
            }
#pragma unroll
            for (int j = 0; j < 8; j++) {
                float ww = w[j] * di;
                ax = fmaf(ww, bf16_lo(v[j]), ax);
                ay = fmaf(ww, bf16_hi(v[j]), ay);
            }
        }
        for (; e < end; e++) {
            int s = esrc[e];
            float ww = dinv[s] * di;
            unsigned int v = xw[(size_t)s * 64 + lane];
            ax = fmaf(ww, bf16_lo(v), ax);
            ay = fmaf(ww, bf16_hi(v), ay);
        }
        float ox = ax + bc.x, oy = ay + bc.y;
        float2 o; o.x = ox; o.y = oy;
        ((float2*)(out + (size_t)node * 128))[lane] = o;
        psx += ox; psy += oy;
        pqx = fmaf(ox, ox, pqx); pqy = fmaf(oy, oy, pqy);
    }

    __shared__ float lsx[256], lsy[256], lqx[256], lqy[256];
    lsx[threadIdx.x] = psx; lsy[threadIdx.x] = psy;
    lqx[threadIdx.x] = pqx; lqy[threadIdx.x] = pqy;
    __syncthreads();
    if (threadIdx.x < 64) {
        int t = threadIdx.x;
        float sx = lsx[t] + lsx[t + 64] + lsx[t + 128] + lsx[t + 192];
        float sy = lsy[t] + lsy[t + 64] + lsy[t + 128] + lsy[t + 192];
        float qx = lqx[t] + lqx[t + 64] + lqx[t + 128] + lqx[t + 192];
        float qy = lqy[t] + lqy[t + 64] + lqy[t + 128] + lqy[t + 192];
        atomicAdd(&sums[2 * t], sx);
        atomicAdd(&sums[2 * t + 1], sy);
        atomicAdd(&sums[128 + 2 * t], qx);
        atomicAdd(&sums[128 + 2 * t + 1], qy);
    }
}

// ---------------- aggregation (64-col output layer) ----------------

__global__ __launch_bounds__(256) void agg64_kernel(const unsigned int* __restrict__ xw,
                                                    const int* __restrict__ rowptr,
                                                    const int* __restrict__ cnt,
                                                    const int* __restrict__ esrc,
                                                    const float* __restrict__ dinv,
                                                    const float* __restrict__ bias,
                                                    float* __restrict__ out, int n) {
    int gid = blockIdx.x * 256 + threadIdx.x;
    int node = gid >> 6;
    int lane = gid & 63;
    if (node >= n) return;
    float di = dinv[node];
    float sw = di * di;
    int beg = rowptr[node];
    int end = beg + cnt[node];

    unsigned int ap = xw[(size_t)node * 32 + (lane >> 1)];
    float a0 = (lane & 1) ? bf16_hi(ap) : bf16_lo(ap);
    float acc = sw * a0;
    int e = beg;
    for (; e + 8 <= end; e += 8) {
        int s[8];
#pragma unroll
        for (int j = 0; j < 8; j++) s[j] = esrc[e + j];
        float w[8];
        unsigned int v[8];
#pragma unroll
        for (int j = 0; j < 8; j++) {
            w[j] = dinv[s[j]];
            v[j] = xw[(size_t)s[j] * 32 + (lane >> 1)];
        }
#pragma unroll
        for (int j = 0; j < 8; j++) {
            float vf = (lane & 1) ? bf16_hi(v[j]) : bf16_lo(v[j]);
            acc = fmaf(w[j] * di, vf, acc);
        }
    }
    for (; e < end; e++) {
        int s = esrc[e];
        unsigned int v = xw[(size_t)s * 32 + (lane >> 1)];
        float vf = (lane & 1) ? bf16_hi(v) : bf16_lo(v);
        acc = fmaf(dinv[s] * di, vf, acc);
    }
    out[(size_t)node * 64 + lane] = acc + bias[lane];
}

// ---------------- BatchNorm finalize ----------------

__global__ void bn_finalize_kernel(const float* __restrict__ sums, const float* __restrict__ g,
                                   const float* __restrict__ be, float* __restrict__ scale,
                                   float* __restrict__ shift, int n) {
    int c = threadIdx.x;  // 128 threads
    float inv_n = 1.0f / (float)n;
    float mean = sums[c] * inv_n;
    float var = sums[128 + c] * inv_n - mean * mean;
    float rstd = rsqrtf(var + BN_EPS);
    float sc = rstd * g[c];
    scale[c] = sc;
    shift[c] = be[c] - mean * sc;
}

// ---------------- launch ----------------

extern "C" void kernel_launch(void* const* d_in, const int* in_sizes, int n_in,
                              void* d_out, int out_size, void* d_ws, size_t ws_size,
                              hipStream_t stream) {
    const float* x   = (const float*)d_in[0];
    const int*   ei  = (const int*)d_in[1];
    const float* W1  = (const float*)d_in[2];
    const float* b1  = (const float*)d_in[3];
    const float* g1  = (const float*)d_in[4];
    const float* be1 = (const float*)d_in[5];
    const float* W2  = (const float*)d_in[6];
    const float* b2  = (const float*)d_in[7];
    const float* g2  = (const float*)d_in[8];
    const float* be2 = (const float*)d_in[9];
    const float* W3  = (const float*)d_in[10];
    const float* b3  = (const float*)d_in[11];

    const int n = in_sizes[0] / 128;
    const int E = in_sizes[1] / 2;
    const int* srcv = ei;
    const int* dstv = ei + E;

    const int G = (E + CHUNK - 1) / CHUNK;      // hist/scatter blocks (196)
    const int HN = BKT * G;                      // H matrix elements (50176)
    const int NB = (n + 511) >> 9;               // used buckets (196)

    char* p = (char*)d_ws;
    auto carve = [&](size_t bytes) -> char* {
        char* q = p;
        p += (bytes + 255) & ~(size_t)255;
        return q;
    };
    int*   cnt    = (int*)carve((size_t)n * 4);
    int*   rowptr = (int*)carve((size_t)n * 4);
    float* dinv   = (float*)carve((size_t)n * 4);
    int*   esrc   = (int*)carve((size_t)E * 4);
    uint2* binned = (uint2*)carve((size_t)E * 8);
    int*   H      = (int*)carve((size_t)HN * 4);
    int*   Hscan  = (int*)carve((size_t)HN * 4);
    float* sums   = (float*)carve(512 * 4);   // [sum1|sq1|sum2|sq2]
    float* bnsc   = (float*)carve(512 * 4);   // [scale1|shift1|scale2|shift2]
    int*   bsum   = (int*)carve(1024 * 4);
    unsigned int* xwb = (unsigned int*)carve((size_t)n * 128 * 2);  // gemm out (bf16 packed)
    float* bufB   = (float*)carve((size_t)n * 128 * 4);             // agg out (fp32)

    hipMemsetAsync(sums, 0, 512 * 4, stream);

    int sbH = (HN + 1023) / 1024;    // 49 <= 256

    // bucketed CSR build (single LDS-atomic build kernel; no global N-scan)
    hist_kernel<<<G, 256, 0, stream>>>(dstv, H, E, G);
    blocksum_kernel<<<sbH, 256, 0, stream>>>(H, bsum, HN);
    scan_bsum_kernel<<<1, 256, 0, stream>>>(bsum, sbH);
    scan_write1_kernel<<<sbH, 256, 0, stream>>>(H, bsum, Hscan, HN);
    bin_scatter_kernel<<<G, 256, 0, stream>>>(srcv, dstv, Hscan, binned, E, G);
    bucket_build_kernel<<<NB, 256, 0, stream>>>(binned, Hscan, cnt, rowptr, dinv, esrc, E, G, n);

    int gb = (n + 63) / 64;
    int ab = (n + 3) / 4;
    const int AG = 2048;   // persistent agg blocks (8/CU)

    // layer 1: gcn(x, W1) + b1   (BN stats fused into agg)
    gemm_kernel<128><<<gb, 256, 0, stream>>>(x, W1, nullptr, nullptr, xwb, n);
    agg128_kernel<<<AG, 256, 0, stream>>>(xwb, rowptr, cnt, esrc, dinv, b1, bufB, sums, n);
    bn_finalize_kernel<<<1, 128, 0, stream>>>(sums, g1, be1, bnsc, bnsc + 128, n);

    // layer 2: gcn(relu(bn1(h)), W2) + b2   (bn1+relu fused into gemm staging)
    gemm_kernel<128><<<gb, 256, 0, stream>>>(bufB, W2, bnsc, bnsc + 128, xwb, n);
    agg128_kernel<<<AG, 256, 0, stream>>>(xwb, rowptr, cnt, esrc, dinv, b2, bufB, sums + 256, n);
    bn_finalize_kernel<<<1, 128, 0, stream>>>(sums + 256, g2, be2, bnsc + 256, bnsc + 384, n);

    // layer 3: gcn(relu(bn2(h)), W3) + b3  -> d_out
    gemm_kernel<64><<<gb, 256, 0, stream>>>(bufB, W3, bnsc + 256, bnsc + 384, xwb, n);
    agg64_kernel<<<ab, 256, 0, stream>>>(xwb, rowptr, cnt, esrc, dinv, b3, (float*)d_out, n);
}

// Round 9
// 612.166 us; speedup vs baseline: 1.4160x; 1.1356x over previous
//
#include <hip/hip_runtime.h>
#include <cstdint>
#include <cstddef>

#define BN_EPS 1e-5f
#define BKT 256        // buckets (dst>>9), 512 nodes each; 100000>>9 = 195 -> 196 used
#define BSH 9
#define CHUNK 8192     // edges per block in hist/scatter

// ---- manual bf16 helpers (hip_bf16.h intrinsics unavailable in this ROCm) ----
__device__ __forceinline__ unsigned int f32_to_bf16_rne(float f) {
    unsigned int u = __float_as_uint(f);
    u += 0x7FFFu + ((u >> 16) & 1u);
    return u >> 16;
}
__device__ __forceinline__ unsigned int pack_bf16x2(float a, float b) {
    return f32_to_bf16_rne(a) | (f32_to_bf16_rne(b) << 16);
}
__device__ __forceinline__ float bf16_lo(unsigned int p) { return __uint_as_float(p << 16); }
__device__ __forceinline__ float bf16_hi(unsigned int p) { return __uint_as_float(p & 0xFFFF0000u); }

// ---------------- bucketed CSR build ----------------
// Phase 1: per-(bucket,block) histogram H[b*G+g]
__global__ void hist_kernel(const int* __restrict__ dst, int* __restrict__ H, int e, int G) {
    __shared__ int h[BKT];
    int t = threadIdx.x, g = blockIdx.x;
    h[t] = 0;
    __syncthreads();
    int base = g * CHUNK;
#pragma unroll
    for (int i = 0; i < CHUNK / 256; i++) {
        int idx = base + i * 256 + t;
        if (idx < e) atomicAdd(&h[dst[idx] >> BSH], 1);
    }
    __syncthreads();
    H[t * G + g] = h[t];
}

// Phase 3: scatter (src,dst) into bucket-contiguous binned array.
__global__ void bin_scatter_kernel(const int* __restrict__ src, const int* __restrict__ dst,
                                   const int* __restrict__ Hscan, uint2* __restrict__ binned,
                                   int e, int G) {
    __shared__ int cur[BKT];
    int t = threadIdx.x, g = blockIdx.x;
    cur[t] = Hscan[t * G + g];
    __syncthreads();
    int base = g * CHUNK;
#pragma unroll
    for (int i = 0; i < CHUNK / 256; i++) {
        int idx = base + i * 256 + t;
        if (idx < e) {
            int s = src[idx], d = dst[idx];
            int pos = atomicAdd(&cur[d >> BSH], 1);
            uint2 v; v.x = (unsigned)s; v.y = (unsigned)d;
            binned[pos] = v;
        }
    }
}

// Phase 4: one block per bucket (512 nodes). Count degrees, local scan,
// write cnt/rowptr/dinv, then fill esrc -- all cursors/counts in LDS.
__global__ __launch_bounds__(256) void bucket_build_kernel(const uint2* __restrict__ binned,
                                                           const int* __restrict__ Hscan,
                                                           int* __restrict__ cnt,
                                                           int* __restrict__ rowptr,
                                                           float* __restrict__ dinv,
                                                           int* __restrict__ esrc,
                                                           int e, int G, int n) {
    __shared__ int lcnt[512], lexc[512], ssum[256];
    const int t = threadIdx.x;
    const int b = blockIdx.x;
    const int start = Hscan[b * G];
    const int end = (b == BKT - 1) ? e : Hscan[(b + 1) * G];

    lcnt[t] = 0; lcnt[t + 256] = 0;
    __syncthreads();
    for (int i = start + t; i < end; i += 256)
        atomicAdd(&lcnt[binned[i].y & 511], 1);
    __syncthreads();

    int a0 = lcnt[2 * t], a1 = lcnt[2 * t + 1];
    ssum[t] = a0 + a1;
    __syncthreads();
    for (int off = 1; off < 256; off <<= 1) {
        int v = (t >= off) ? ssum[t - off] : 0;
        __syncthreads();
        ssum[t] += v;
        __syncthreads();
    }
    int excl = (t == 0) ? 0 : ssum[t - 1];
    lexc[2 * t] = excl;
    lexc[2 * t + 1] = excl + a0;
    __syncthreads();

    int nodebase = b << BSH;
#pragma unroll
    for (int j2 = 0; j2 < 2; j2++) {
        int j = 2 * t + j2;
        int node = nodebase + j;
        if (node < n) {
            int c = lcnt[j];
            cnt[node] = c;
            rowptr[node] = start + lexc[j];
            dinv[node] = rsqrtf((float)(c + 1));
        }
    }
    __syncthreads();

    for (int i = start + t; i < end; i += 256) {
        uint2 ed = binned[i];
        int pos = start + atomicAdd(&lexc[ed.y & 511], 1);
        esrc[pos] = (int)ed.x;
    }
}

// ---- scan helpers for H (bucket-major (bucket,block) histogram) ----

__global__ void blocksum_kernel(const int* __restrict__ in, int* __restrict__ bsum, int n) {
    int t = threadIdx.x;
    int base = blockIdx.x * 1024 + t * 4;
    int s = 0;
    if (base + 3 < n) {
        int4 v = *(const int4*)&in[base];
        s = v.x + v.y + v.z + v.w;
    } else {
        for (int j = 0; j < 4; j++) if (base + j < n) s += in[base + j];
    }
    __shared__ int ls[256];
    ls[t] = s;
    __syncthreads();
    for (int off = 128; off > 0; off >>= 1) {
        if (t < off) ls[t] += ls[t + off];
        __syncthreads();
    }
    if (t == 0) bsum[blockIdx.x] = ls[0];
}

__global__ void scan_bsum_kernel(int* __restrict__ bsum, int nb) {
    int t = threadIdx.x;
    __shared__ int ls[256];
    int v = (t < nb) ? bsum[t] : 0;
    ls[t] = v;
    __syncthreads();
    for (int off = 1; off < 256; off <<= 1) {
        int p = (t >= off) ? ls[t - off] : 0;
        __syncthreads();
        ls[t] += p;
        __syncthreads();
    }
    if (t < nb) bsum[t] = ls[t] - v;   // inclusive -> exclusive
}

__global__ void scan_write1_kernel(const int* __restrict__ in, const int* __restrict__ bsum,
                                   int* __restrict__ out, int n) {
    int t = threadIdx.x;
    int base = blockIdx.x * 1024 + t * 4;
    int v[4];
    int s = 0;
    if (base + 3 < n) {
        int4 q = *(const int4*)&in[base];
        v[0] = q.x; v[1] = q.y; v[2] = q.z; v[3] = q.w;
        s = q.x + q.y + q.z + q.w;
    } else {
        for (int j = 0; j < 4; j++) { v[j] = (base + j < n) ? in[base + j] : 0; s += v[j]; }
    }
    __shared__ int ls[256];
    ls[t] = s;
    __syncthreads();
    for (int off = 1; off < 256; off <<= 1) {
        int p = (t >= off) ? ls[t - off] : 0;
        __syncthreads();
        ls[t] += p;
        __syncthreads();
    }
    int run = bsum[blockIdx.x] + ls[t] - s;
    if (base + 3 < n) {
        int4 r; r.x = run; r.y = run + v[0]; r.z = run + v[0] + v[1]; r.w = run + v[0] + v[1] + v[2];
        *(int4*)&out[base] = r;
    } else {
        for (int j = 0; j < 4; j++) {
            if (base + j < n) out[base + j] = run;
            run += v[j];
        }
    }
}

// ---------------- GEMM: Y[n,OUTC](bf16) = act(X[n,128]) @ W[128,OUTC] ----------------

template <int OUTC>
__global__ __launch_bounds__(256) void gemm_kernel(const float* __restrict__ X,
                                                   const float* __restrict__ W,
                                                   const float* __restrict__ scale,
                                                   const float* __restrict__ shift,
                                                   unsigned int* __restrict__ Y, int n) {
    constexpr int RPT = (OUTC == 128) ? 8 : 4;  // rows per thread
    constexpr int CG  = OUTC / 4;               // col groups (4 cols each)
    __shared__ float lXT[128 * 68];             // [k][row], 34.8 KB
    const int t = threadIdx.x;
    const int base = blockIdx.x * 64;
    const bool bn = (scale != nullptr);

#pragma unroll
    for (int i = 0; i < 8; i++) {
        int id = i * 256 + t;
        int k  = id & 127;
        int r4 = id >> 7;  // 0..15
        float sc = 1.0f, sh = 0.0f;
        if (bn) { sc = scale[k]; sh = shift[k]; }
        float v[4];
#pragma unroll
        for (int j = 0; j < 4; j++) {
            int r = base + r4 * 4 + j;
            float xv = 0.0f;
            if (r < n) xv = X[(size_t)r * 128 + k];
            if (bn) xv = fmaxf(fmaf(xv, sc, sh), 0.0f);
            v[j] = xv;
        }
        float4 vv; vv.x = v[0]; vv.y = v[1]; vv.z = v[2]; vv.w = v[3];
        *(float4*)&lXT[k * 68 + r4 * 4] = vv;
    }
    __syncthreads();

    const int cg = t % CG;
    const int rg = t / CG;
    float acc[RPT][4];
#pragma unroll
    for (int i = 0; i < RPT; i++)
#pragma unroll
        for (int j = 0; j < 4; j++) acc[i][j] = 0.0f;

#pragma unroll 4
    for (int k = 0; k < 128; k++) {
        float4 b = *(const float4*)&W[k * OUTC + cg * 4];
        float a[RPT];
        *(float4*)&a[0] = *(const float4*)&lXT[k * 68 + rg * RPT];
        if constexpr (RPT == 8)
            *(float4*)&a[4] = *(const float4*)&lXT[k * 68 + rg * RPT + 4];
#pragma unroll
        for (int i = 0; i < RPT; i++) {
            acc[i][0] = fmaf(a[i], b.x, acc[i][0]);
            acc[i][1] = fmaf(a[i], b.y, acc[i][1]);
            acc[i][2] = fmaf(a[i], b.z, acc[i][2]);
            acc[i][3] = fmaf(a[i], b.w, acc[i][3]);
        }
    }

#pragma unroll
    for (int i = 0; i < RPT; i++) {
        int r = base + rg * RPT + i;
        if (r < n) {
            uint2 o;
            o.x = pack_bf16x2(acc[i][0], acc[i][1]);
            o.y = pack_bf16x2(acc[i][2], acc[i][3]);
            *(uint2*)&Y[(size_t)r * (OUTC / 2) + cg * 2] = o;
        }
    }
}

// ---------------- aggregation (128 cols): one wave per node (R6 winner) ----------------
// out[i] = sum_{e:dst=i} dinv[src_e]*dinv[i] * xw[src_e] + dinv[i]^2 * xw[i] + bias
// lane owns cols 2l,2l+1 via one uint gather (4B); 8-wide edge batching.

__global__ __launch_bounds__(256) void agg128_kernel(const unsigned int* __restrict__ xw,
                                                     const int* __restrict__ rowptr,
                                                     const int* __restrict__ cnt,
                                                     const int* __restrict__ esrc,
                                                     const float* __restrict__ dinv,
                                                     const float* __restrict__ bias,
                                                     float* __restrict__ out, int n) {
    int gid = blockIdx.x * 256 + threadIdx.x;
    int node = gid >> 6;
    int lane = gid & 63;
    if (node >= n) return;
    float di = dinv[node];
    float sw = di * di;
    int beg = rowptr[node];
    int end = beg + cnt[node];

    unsigned int ap = xw[(size_t)node * 64 + lane];
    float ax = sw * bf16_lo(ap), ay = sw * bf16_hi(ap);
    int e = beg;
    for (; e + 8 <= end; e += 8) {
        int s[8];
#pragma unroll
        for (int j = 0; j < 8; j++) s[j] = esrc[e + j];
        float w[8];
        unsigned int v[8];
#pragma unroll
        for (int j = 0; j < 8; j++) {
            w[j] = dinv[s[j]];
            v[j] = xw[(size_t)s[j] * 64 + lane];
        }
#pragma unroll
        for (int j = 0; j < 8; j++) {
            float ww = w[j] * di;
            ax = fmaf(ww, bf16_lo(v[j]), ax);
            ay = fmaf(ww, bf16_hi(v[j]), ay);
        }
    }
    for (; e < end; e++) {
        int s = esrc[e];
        float ww = dinv[s] * di;
        unsigned int v = xw[(size_t)s * 64 + lane];
        ax = fmaf(ww, bf16_lo(v), ax);
        ay = fmaf(ww, bf16_hi(v), ay);
    }
    float2 b = ((const float2*)bias)[lane];
    float2 o; o.x = ax + b.x; o.y = ay + b.y;
    ((float2*)(out + (size_t)node * 128))[lane] = o;
}

// ---------------- aggregation (64-col output layer) ----------------

__global__ __launch_bounds__(256) void agg64_kernel(const unsigned int* __restrict__ xw,
                                                    const int* __restrict__ rowptr,
                                                    const int* __restrict__ cnt,
                                                    const int* __restrict__ esrc,
                                                    const float* __restrict__ dinv,
                                                    const float* __restrict__ bias,
                                                    float* __restrict__ out, int n) {
    int gid = blockIdx.x * 256 + threadIdx.x;
    int node = gid >> 6;
    int lane = gid & 63;
    if (node >= n) return;
    float di = dinv[node];
    float sw = di * di;
    int beg = rowptr[node];
    int end = beg + cnt[node];

    unsigned int ap = xw[(size_t)node * 32 + (lane >> 1)];
    float a0 = (lane & 1) ? bf16_hi(ap) : bf16_lo(ap);
    float acc = sw * a0;
    int e = beg;
    for (; e + 8 <= end; e += 8) {
        int s[8];
#pragma unroll
        for (int j = 0; j < 8; j++) s[j] = esrc[e + j];
        float w[8];
        unsigned int v[8];
#pragma unroll
        for (int j = 0; j < 8; j++) {
            w[j] = dinv[s[j]];
            v[j] = xw[(size_t)s[j] * 32 + (lane >> 1)];
        }
#pragma unroll
        for (int j = 0; j < 8; j++) {
            float vf = (lane & 1) ? bf16_hi(v[j]) : bf16_lo(v[j]);
            acc = fmaf(w[j] * di, vf, acc);
        }
    }
    for (; e < end; e++) {
        int s = esrc[e];
        unsigned int v = xw[(size_t)s * 32 + (lane >> 1)];
        float vf = (lane & 1) ? bf16_hi(v) : bf16_lo(v);
        acc = fmaf(dinv[s] * di, vf, acc);
    }
    out[(size_t)node * 64 + lane] = acc + bias[lane];
}

// ---------------- BatchNorm (training-mode, biased var) ----------------

__global__ void bn_stats_kernel(const float* __restrict__ h, float* __restrict__ sums, int n) {
    int c = threadIdx.x & 127;
    int half = threadIdx.x >> 7;
    float s = 0.0f, q = 0.0f;
    for (int r = blockIdx.x * 2 + half; r < n; r += gridDim.x * 2) {
        float v = h[(size_t)r * 128 + c];
        s += v;
        q = fmaf(v, v, q);
    }
    __shared__ float ls[256], lq[256];
    ls[threadIdx.x] = s; lq[threadIdx.x] = q;
    __syncthreads();
    if (half == 0) {
        s += ls[c + 128];
        q += lq[c + 128];
        atomicAdd(&sums[c], s);
        atomicAdd(&sums[128 + c], q);
    }
}

__global__ void bn_finalize_kernel(const float* __restrict__ sums, const float* __restrict__ g,
                                   const float* __restrict__ be, float* __restrict__ scale,
                                   float* __restrict__ shift, int n) {
    int c = threadIdx.x;  // 128 threads
    float inv_n = 1.0f / (float)n;
    float mean = sums[c] * inv_n;
    float var = sums[128 + c] * inv_n - mean * mean;
    float rstd = rsqrtf(var + BN_EPS);
    float sc = rstd * g[c];
    scale[c] = sc;
    shift[c] = be[c] - mean * sc;
}

// ---------------- launch ----------------

extern "C" void kernel_launch(void* const* d_in, const int* in_sizes, int n_in,
                              void* d_out, int out_size, void* d_ws, size_t ws_size,
                              hipStream_t stream) {
    const float* x   = (const float*)d_in[0];
    const int*   ei  = (const int*)d_in[1];
    const float* W1  = (const float*)d_in[2];
    const float* b1  = (const float*)d_in[3];
    const float* g1  = (const float*)d_in[4];
    const float* be1 = (const float*)d_in[5];
    const float* W2  = (const float*)d_in[6];
    const float* b2  = (const float*)d_in[7];
    const float* g2  = (const float*)d_in[8];
    const float* be2 = (const float*)d_in[9];
    const float* W3  = (const float*)d_in[10];
    const float* b3  = (const float*)d_in[11];

    const int n = in_sizes[0] / 128;
    const int E = in_sizes[1] / 2;
    const int* srcv = ei;
    const int* dstv = ei + E;

    const int G = (E + CHUNK - 1) / CHUNK;      // hist/scatter blocks (196)
    const int HN = BKT * G;                      // H matrix elements (50176)
    const int NB = (n + 511) >> 9;               // used buckets (196)

    char* p = (char*)d_ws;
    auto carve = [&](size_t bytes) -> char* {
        char* q = p;
        p += (bytes + 255) & ~(size_t)255;
        return q;
    };
    int*   cnt    = (int*)carve((size_t)n * 4);
    int*   rowptr = (int*)carve((size_t)n * 4);
    float* dinv   = (float*)carve((size_t)n * 4);
    int*   esrc   = (int*)carve((size_t)E * 4);
    uint2* binned = (uint2*)carve((size_t)E * 8);
    int*   H      = (int*)carve((size_t)HN * 4);
    int*   Hscan  = (int*)carve((size_t)HN * 4);
    float* sums   = (float*)carve(512 * 4);   // [sum1|sq1|sum2|sq2]
    float* bnsc   = (float*)carve(512 * 4);   // [scale1|shift1|scale2|shift2]
    int*   bsum   = (int*)carve(1024 * 4);
    unsigned int* xwb = (unsigned int*)carve((size_t)n * 128 * 2);  // gemm out (bf16 packed)
    float* bufB   = (float*)carve((size_t)n * 128 * 4);             // agg out (fp32)

    hipMemsetAsync(sums, 0, 512 * 4, stream);

    int sbH = (HN + 1023) / 1024;    // 49 <= 256

    // bucketed CSR build (single LDS-atomic build kernel; no global N-scan)
    hist_kernel<<<G, 256, 0, stream>>>(dstv, H, E, G);
    blocksum_kernel<<<sbH, 256, 0, stream>>>(H, bsum, HN);
    scan_bsum_kernel<<<1, 256, 0, stream>>>(bsum, sbH);
    scan_write1_kernel<<<sbH, 256, 0, stream>>>(H, bsum, Hscan, HN);
    bin_scatter_kernel<<<G, 256, 0, stream>>>(srcv, dstv, Hscan, binned, E, G);
    bucket_build_kernel<<<NB, 256, 0, stream>>>(binned, Hscan, cnt, rowptr, dinv, esrc, E, G, n);

    int gb = (n + 63) / 64;
    int ab = (n + 3) / 4;   // one wave per node

    // layer 1: gcn(x, W1) + b1
    gemm_kernel<128><<<gb, 256, 0, stream>>>(x, W1, nullptr, nullptr, xwb, n);
    agg128_kernel<<<ab, 256, 0, stream>>>(xwb, rowptr, cnt, esrc, dinv, b1, bufB, n);
    bn_stats_kernel<<<512, 256, 0, stream>>>(bufB, sums, n);
    bn_finalize_kernel<<<1, 128, 0, stream>>>(sums, g1, be1, bnsc, bnsc + 128, n);

    // layer 2: gcn(relu(bn1(h)), W2) + b2   (bn1+relu fused into gemm staging)
    gemm_kernel<128><<<gb, 256, 0, stream>>>(bufB, W2, bnsc, bnsc + 128, xwb, n);
    agg128_kernel<<<ab, 256, 0, stream>>>(xwb, rowptr, cnt, esrc, dinv, b2, bufB, n);
    bn_stats_kernel<<<512, 256, 0, stream>>>(bufB, sums + 256, n);
    bn_finalize_kernel<<<1, 128, 0, stream>>>(sums + 256, g2, be2, bnsc + 256, bnsc + 384, n);

    // layer 3: gcn(relu(bn2(h)), W3) + b3  -> d_out
    gemm_kernel<64><<<gb, 256, 0, stream>>>(bufB, W3, bnsc + 256, bnsc + 384, xwb, n);
    agg64_kernel<<<ab, 256, 0, stream>>>(xwb, rowptr, cnt, esrc, dinv, b3, (float*)d_out, n);
}